// Round 15
// baseline (123.685 us; speedup 1.0000x reference)
//
#include <hip/hip_runtime.h>

// Problem constants (from reference)
#define NSTARS 2048
#define BATCH  256
#define PF     28
#define NGE    512
#define GF     32
#define OPD2   65536   // 256*256
#define KTOT   (PF + GF)  // 60

// workspace layout
#define WA_OFF 61440                     // Wt: 60*256*4 = 61440 B
#define WA_HALF 32768                    // one A-frag stream: 16*2*64*16 B
#define WS_NEED (WA_OFF + 2 * WA_HALF)   // 126,976 B

typedef float f32x4 __attribute__((ext_vector_type(4)));
typedef short bf16x8 __attribute__((ext_vector_type(8)));
typedef unsigned int u32;

// ---------------------------------------------------------------------------
// Kernel 1: index search + W = [interm_poly | interm_graph] (k-major layout)
// Wt[k*BATCH + b], k in [0,60)
// ---------------------------------------------------------------------------
__global__ __launch_bounds__(256) void prep_kernel(
    const float* __restrict__ positions,  const float* __restrict__ obs_pos,
    const float* __restrict__ poly_dic,   const float* __restrict__ graph_dic,
    const float* __restrict__ alpha_poly, const float* __restrict__ alpha_graph,
    float* __restrict__ Wt)
{
    const int b = blockIdx.x;   // batch row
    const int t = threadIdx.x;  // 256 threads

    const float p0 = positions[2 * b];
    const float p1 = positions[2 * b + 1];

    // Faithful to argmax(eq.reshape(B,-1))//2 : first star n (row-major over
    // (n, coord)) where EITHER coordinate matches; all-false -> 0.
    int cand = 0x7fffffff;
    #pragma unroll
    for (int i = 0; i < NSTARS / 256; ++i) {
        const int n = t + i * 256;
        const float o0 = obs_pos[2 * n];
        const float o1 = obs_pos[2 * n + 1];
        if (o0 == p0 || o1 == p1) cand = min(cand, n);
    }
    __shared__ int smin[256];
    smin[t] = cand;
    __syncthreads();
    for (int s = 128; s > 0; s >>= 1) {
        if (t < s) smin[t] = min(smin[t], smin[t + s]);
        __syncthreads();
    }
    int idx = smin[0];
    if (idx == 0x7fffffff) idx = 0;  // argmax of all-False returns 0

    // interm_poly[j] = sum_p poly_dic[idx,p] * alpha_poly[p,j]
    if (t < PF) {
        float acc = 0.f;
        #pragma unroll
        for (int p = 0; p < PF; ++p)
            acc += poly_dic[idx * PF + p] * alpha_poly[p * PF + t];
        Wt[t * BATCH + b] = acc;
    }

    // interm_graph[g] = sum_e graph_dic[idx,e] * alpha_graph[e,g]
    __shared__ float psum[8][GF];
    {
        const int g = t & 31;
        const int r = t >> 5;
        float acc = 0.f;
        const int e0 = r * (NGE / 8);
        for (int e = e0; e < e0 + NGE / 8; ++e)
            acc += graph_dic[idx * NGE + e] * alpha_graph[e * GF + g];
        psum[r][g] = acc;
    }
    __syncthreads();
    if (t < GF) {
        float acc = 0.f;
        #pragma unroll
        for (int r = 0; r < 8; ++r) acc += psum[r][t];
        Wt[(PF + t) * BATCH + b] = acc;
    }
}

// ---------------------------------------------------------------------------
// bf16 RNE helpers
// ---------------------------------------------------------------------------
__device__ __forceinline__ u32 bf16_rne(u32 x) {       // fp32 bits -> bf16 (low 16)
    return (x + 0x7FFFu + ((x >> 16) & 1u)) >> 16;
}
__device__ __forceinline__ float bf16_to_f32(u32 h) {  // bf16 (low 16) -> fp32
    return __uint_as_float(h << 16);
}

// ---------------------------------------------------------------------------
// Kernel 1b: W (fp32, k-major) -> TWO bf16 A-fragment streams:
//   Wa_hi = bf16(W),  Wa_lo = bf16(W - float(Wa_hi))   (error ~2^-18 rel)
// A-frag (16x16x32 bf16): lane l holds 8 bf16; m = l&15, k = 32*kf+(l>>4)*8+e.
// Stream index: ((mtile*2+kf)*64 + lane)*16B; k >= 60 zero-padded (exact).
// PROVEN in R14 (passed).
// ---------------------------------------------------------------------------
__global__ __launch_bounds__(256) void prep2_kernel(
    const float* __restrict__ Wt, u32* __restrict__ Wa_hi, u32* __restrict__ Wa_lo)
{
    const int f     = blockIdx.x * 256 + threadIdx.x;  // 0..2047
    const int lane  = f & 63;
    const int kf    = (f >> 6) & 1;
    const int mtile = f >> 7;                          // 0..15
    const int m     = mtile * 16 + (lane & 15);
    const int kbase = kf * 32 + (lane >> 4) * 8;
    u32 hi_pk[4], lo_pk[4];
    #pragma unroll
    for (int p = 0; p < 4; ++p) {
        u32 h[2], l[2];
        #pragma unroll
        for (int q = 0; q < 2; ++q) {
            const int k = kbase + 2 * p + q;
            float w = (k < KTOT) ? Wt[k * BATCH + m] : 0.f;
            const u32 hb = bf16_rne(__float_as_uint(w));
            const float resid = w - bf16_to_f32(hb);
            h[q] = hb;
            l[q] = bf16_rne(__float_as_uint(resid));
        }
        hi_pk[p] = h[0] | (h[1] << 16);
        lo_pk[p] = l[0] | (l[1] << 16);
    }
    *reinterpret_cast<f32x4*>(Wa_hi + f * 4) = *reinterpret_cast<f32x4*>(hi_pk);
    *reinterpret_cast<f32x4*>(Wa_lo + f * 4) = *reinterpret_cast<f32x4*>(lo_pk);
}

// ---------------------------------------------------------------------------
// Kernel 2 (fused MFMA): out[b][ij] = sum_k W[k][b]*S[k][ij], 16x16x32 bf16,
// W = W_hi + W_lo double-bf16. R14's kernel + in-kernel S conversion:
//  - STAGE: thread (wave w, lane l) builds frags f = w*8..w*8+7 in LDS.
//    Per frag-lane: gather 8 fp32 from k-major S (lanes 0-15 share a 64 B
//    segment -> 4 segments/instr), RNE-pack to 4 u32, ONE contiguous
//    ds_write_b128 (conflict-free). One barrier. Eliminates R14's
//    conv_kernel (launch + 24 MB Sb round trip + serial dependency).
//  - MFMA loop identical to R14 (passed): wave w owns 4 ij-tiles x 4
//    M-tiles, B-frags now via linear ds_read_b128 (canonical, conflict-
//    free). D layout (m89-verified): col=lane&15, row=(lane>>4)*4+reg.
//  - Per-XCD fp32 S gather = 2 MB x4 y-reuse, L2-resident (XCD swizzle).
//  - LDS 32 KB -> 4-5 blocks/CU. Zero other barriers. nt stores.
// ---------------------------------------------------------------------------
__global__ __launch_bounds__(256) void mfma_kernel(
    const float* __restrict__ S_poly, const float* __restrict__ S_graph,
    const u32* __restrict__ Wa_hi, const u32* __restrict__ Wa_lo,
    float* __restrict__ out)
{
    __shared__ u32 sfrag[32 * 256];         // 32 frags x 64 lanes x 16 B = 32 KB

    const int t    = threadIdx.x;
    const int id   = blockIdx.x;            // 0..1023
    const int xcd  = id & 7;
    const int slot = id >> 3;               // 0..127
    const int xb   = xcd * 32 + (slot & 31);// 0..255 (32 x-chunks per XCD)
    const int yb   = slot >> 5;             // 0..3
    const int w    = t >> 6;                // wave 0..3
    const int lane = t & 63;
    const int b0   = yb * 64;
    const int ij0  = xb * 256;              // block's 256-ij x-chunk

    // ---- STAGE: build B-frags for 16 tiles x 2 kf in LDS ----
    #pragma unroll
    for (int i = 0; i < 8; ++i) {
        const int f    = w * 8 + i;         // 0..31
        const int tile = f >> 1;            // local ij-tile 0..15
        const int kf   = f & 1;
        const int ij   = ij0 + tile * 16 + (lane & 15);
        const int kb   = kf * 32 + (lane >> 4) * 8;
        u32 pk[4];
        #pragma unroll
        for (int p = 0; p < 4; ++p) {
            u32 lo = 0u, hi = 0u;
            const int k0 = kb + 2 * p, k1 = k0 + 1;
            if (k0 < KTOT)
                lo = bf16_rne(__float_as_uint(
                    k0 < PF ? S_poly[(size_t)k0 * OPD2 + ij]
                            : S_graph[(size_t)(k0 - PF) * OPD2 + ij]));
            if (k1 < KTOT)
                hi = bf16_rne(__float_as_uint(
                    k1 < PF ? S_poly[(size_t)k1 * OPD2 + ij]
                            : S_graph[(size_t)(k1 - PF) * OPD2 + ij]));
            pk[p] = lo | (hi << 16);
        }
        *reinterpret_cast<f32x4*>(&sfrag[f * 256 + lane * 4]) =
            *reinterpret_cast<f32x4*>(pk);
    }

    // A-frags: 4 M-tiles x 2 kf x {hi,lo} (16 x 16 B, global, tiny)
    bf16x8 Ah[4][2], Al[4][2];
    #pragma unroll
    for (int mt = 0; mt < 4; ++mt)
        #pragma unroll
        for (int kf = 0; kf < 2; ++kf) {
            const int fi = (((yb * 4 + mt) * 2 + kf) * 64 + lane) * 4;
            Ah[mt][kf] = *reinterpret_cast<const bf16x8*>(Wa_hi + fi);
            Al[mt][kf] = *reinterpret_cast<const bf16x8*>(Wa_lo + fi);
        }

    __syncthreads();   // frags visible to all waves (the kernel's only barrier)

    const int row = (lane >> 4) * 4;   // D row base (batch)
    const int col = lane & 15;         // D col (ij)

    #pragma unroll
    for (int tt = 0; tt < 4; ++tt) {
        const int lt = w * 4 + tt;          // local tile 0..15
        const int T  = xb * 16 + lt;        // global ij-tile
        const bf16x8 B0 = *reinterpret_cast<const bf16x8*>(
            &sfrag[(lt * 2 + 0) * 256 + lane * 4]);
        const bf16x8 B1 = *reinterpret_cast<const bf16x8*>(
            &sfrag[(lt * 2 + 1) * 256 + lane * 4]);
        #pragma unroll
        for (int mt = 0; mt < 4; ++mt) {
            f32x4 acc = (f32x4)(0.f);
            acc = __builtin_amdgcn_mfma_f32_16x16x32_bf16(Al[mt][0], B0, acc, 0, 0, 0);
            acc = __builtin_amdgcn_mfma_f32_16x16x32_bf16(Al[mt][1], B1, acc, 0, 0, 0);
            acc = __builtin_amdgcn_mfma_f32_16x16x32_bf16(Ah[mt][0], B0, acc, 0, 0, 0);
            acc = __builtin_amdgcn_mfma_f32_16x16x32_bf16(Ah[mt][1], B1, acc, 0, 0, 0);
            float* op = out + (size_t)(b0 + mt * 16 + row) * OPD2 + T * 16 + col;
            #pragma unroll
            for (int j = 0; j < 4; ++j)
                __builtin_nontemporal_store(acc[j], op + (size_t)j * OPD2);
        }
    }
}

// ---------------------------------------------------------------------------
// Fallback (fp32, proven-correct R1-style) if workspace too small.
// ---------------------------------------------------------------------------
__global__ __launch_bounds__(256) void fb_kernel(
    const float* __restrict__ S_poly, const float* __restrict__ S_graph,
    const float* __restrict__ Wt, float* __restrict__ out)
{
    const int t  = threadIdx.x;
    const int ij = blockIdx.x * 1024 + t * 4;
    const int b0 = blockIdx.y * 16;
    f32x4 acc[16];
    #pragma unroll
    for (int b = 0; b < 16; ++b) acc[b] = (f32x4)(0.f);
    const float* __restrict__ wp = Wt + b0;
    #pragma unroll 2
    for (int k = 0; k < PF; ++k) {
        const f32x4 s = *reinterpret_cast<const f32x4*>(S_poly + (size_t)k * OPD2 + ij);
        #pragma unroll
        for (int b = 0; b < 16; ++b) acc[b] += wp[k * BATCH + b] * s;
    }
    #pragma unroll 2
    for (int k = 0; k < GF; ++k) {
        const f32x4 s = *reinterpret_cast<const f32x4*>(S_graph + (size_t)k * OPD2 + ij);
        #pragma unroll
        for (int b = 0; b < 16; ++b) acc[b] += wp[(PF + k) * BATCH + b] * s;
    }
    #pragma unroll
    for (int b = 0; b < 16; ++b)
        *reinterpret_cast<f32x4*>(out + (size_t)(b0 + b) * OPD2 + ij) = acc[b];
}

// ---------------------------------------------------------------------------
extern "C" void kernel_launch(void* const* d_in, const int* in_sizes, int n_in,
                              void* d_out, int out_size, void* d_ws, size_t ws_size,
                              hipStream_t stream) {
    const float* positions   = (const float*)d_in[0];  // (256, 2)
    const float* obs_pos     = (const float*)d_in[1];  // (2048, 2)
    const float* poly_dic    = (const float*)d_in[2];  // (2048, 28)
    const float* graph_dic   = (const float*)d_in[3];  // (2048, 512)
    const float* alpha_poly  = (const float*)d_in[4];  // (28, 28)
    const float* alpha_graph = (const float*)d_in[5];  // (512, 32)
    const float* S_poly      = (const float*)d_in[6];  // (28, 256, 256)
    const float* S_graph     = (const float*)d_in[7];  // (32, 256, 256)
    float* out = (float*)d_out;                        // (256, 256, 256)

    float* Wt = (float*)d_ws;

    prep_kernel<<<BATCH, 256, 0, stream>>>(positions, obs_pos, poly_dic,
                                           graph_dic, alpha_poly, alpha_graph,
                                           Wt);

    if (ws_size >= WS_NEED) {
        u32* Wa_hi = (u32*)((char*)d_ws + WA_OFF);
        u32* Wa_lo = (u32*)((char*)d_ws + WA_OFF + WA_HALF);
        prep2_kernel<<<8, 256, 0, stream>>>(Wt, Wa_hi, Wa_lo);
        mfma_kernel<<<1024, 256, 0, stream>>>(S_poly, S_graph, Wa_hi, Wa_lo, out);
    } else {
        dim3 grid(OPD2 / 1024, BATCH / 16);
        fb_kernel<<<grid, 256, 0, stream>>>(S_poly, S_graph, Wt, out);
    }
}